// Round 8
// baseline (1625.717 us; speedup 1.0000x reference)
//
#include <hip/hip_runtime.h>
#include <stdint.h>

// x (16,256,64,64) fp32; 32 groups; 8 heads; head dim 32. All I/O fp32.
// Intermediates bf16. Softmax folded: att = diag(1/l) * sum_n exp(k) v.
// R7: att-output folds into w_proj: W2_b = wp @ blockdiag(att/l).
// R9: Q never materialized: out = (W2_b @ Wq_q) @ xn  (W3 = W2@Wq_q per batch).
// R10: kv_att single-pass 128x128 (64 K + 64 V rows).
// R13: ONE plain (graph-capturable) kernel, NO barriers: global in-order task
//      queue + per-batch/tile done-counters with agent-scope release/acquire.
//      R6/R7 post-mortem: grid.sync() = 1140us spin pathology & not capturable;
//      dataflow spins are fine-grained and phases overlap. Deadlock-free by
//      in-order claiming (a task only depends on lower-indexed tasks), no
//      co-residency assumption. Task bodies = R5 verbatim (proven 208us).
//      Control block (2.3KB) zeroed via hipMemsetAsync (graph-legal).
#define BATCH 16
#define CCH   256
#define NSP   4096

typedef unsigned short u16;
typedef short  short8 __attribute__((ext_vector_type(8)));   // 8 bf16 (4 VGPRs)
typedef float  f32x4  __attribute__((ext_vector_type(4)));

__device__ __forceinline__ float bf2f(u16 h) {
  union { unsigned int u; float f; } x; x.u = ((unsigned int)h) << 16; return x.f;
}
__device__ __forceinline__ u16 f2bf(float f) {
  union { float f; unsigned int u; } x; x.f = f;
  unsigned int r = 0x7fffu + ((x.u >> 16) & 1u);
  return (u16)((x.u + r) >> 16);
}

#define GLB(p) ((__attribute__((address_space(1))) void*)(p))
#define LDSP(p) ((__attribute__((address_space(3))) void*)(p))

// ------------------------------------------------ dataflow sync primitives
// Producer: block-wide writes done -> release add (L2 writeback, agent scope).
__device__ __forceinline__ void signal(int* c, int tid) {
  __syncthreads();
  if (tid == 0)
    __hip_atomic_fetch_add(c, 1, __ATOMIC_RELEASE, __HIP_MEMORY_SCOPE_AGENT);
}
// Consumer: relaxed poll (no cache nuking) + one acquire fence on success.
__device__ __forceinline__ void wait_ge(int* c, int target, int tid) {
  if (tid == 0)
    while (__hip_atomic_load(c, __ATOMIC_RELAXED, __HIP_MEMORY_SCOPE_AGENT) < target)
      __builtin_amdgcn_s_sleep(2);
  __syncthreads();
  __threadfence();                              // acquire: invalidate stale lines
}

// ------------------------------------------------ phase A body: GN stats +
// att4 zero (own batch's region only) + weights fp32->bf16 + wqT transpose.
__device__ __forceinline__ void prep_body(int blk, int tid, const float* x,
                                          const float* wq, const float* wp,
                                          float2* stats, float* att4,
                                          u16* wbf, u16* wqT, u16* smem) {
  if (blk < 512) {
    float* red = (float*)(smem + 4608);         // bytes 9216.. (past ls region)
    {
      float* az = att4 + (size_t)blk * 264;     // zero 128*1056 over 512 blocks
      for (int i = tid; i < 264; i += 256) az[i] = 0.f;
    }
    const float4* xv = (const float4*)(x + (size_t)blk * 32768);
    float s = 0.f, ss = 0.f;
    for (int i = tid; i < 8192; i += 256) {
      float4 u = xv[i];
      s  += u.x + u.y + u.z + u.w;
      ss += u.x * u.x + u.y * u.y + u.z * u.z + u.w * u.w;
    }
#pragma unroll
    for (int off = 32; off > 0; off >>= 1) {
      s  += __shfl_down(s, off);
      ss += __shfl_down(ss, off);
    }
    const int wave = tid >> 6, lane = tid & 63;
    if (lane == 0) { red[wave * 2] = s; red[wave * 2 + 1] = ss; }
    __syncthreads();
    if (tid == 0) {
      const float S  = red[0] + red[2] + red[4] + red[6];
      const float SS = red[1] + red[3] + red[5] + red[7];
      const float mean = S * (1.f / 32768.f);
      const float var  = SS * (1.f / 32768.f) - mean * mean;
      stats[blk] = make_float2(mean, rsqrtf(var + 1e-5f));
    }
  } else if (blk < 768) {
    const int i = ((blk - 512) * 256 + tid) * 4;
    float4 v = (i < 196608) ? *(const float4*)(wq + i)
                            : *(const float4*)(wp + (i - 196608));
    ushort4 o;
    o.x = f2bf(v.x); o.y = f2bf(v.y); o.z = f2bf(v.z); o.w = f2bf(v.w);
    *(ushort4*)(wbf + i) = o;
  } else {
    u16 (*ls)[72] = (u16(*)[72])smem;
    const int t2 = blk - 768;
    const int c0 = (t2 & 3) * 64, r0 = (t2 >> 2) * 64;
#pragma unroll
    for (int j = 0; j < 4; ++j) {
      const int row = j * 16 + (tid >> 4), col = (tid & 15) * 4;
      float4 u = *(const float4*)(wq + (r0 + row) * 256 + c0 + col);
      ls[row][col]     = f2bf(u.x);
      ls[row][col + 1] = f2bf(u.y);
      ls[row][col + 2] = f2bf(u.z);
      ls[row][col + 3] = f2bf(u.w);
    }
    __syncthreads();
#pragma unroll
    for (int j = 0; j < 2; ++j) {
      const int crow = j * 32 + (tid >> 3), d8 = (tid & 7) * 8;
      u16 tmp[8];
#pragma unroll
      for (int k = 0; k < 8; ++k) tmp[k] = ls[d8 + k][crow];
      *(uint4*)(wqT + (c0 + crow) * 256 + r0 + d8) = *(uint4*)tmp;
    }
  }
}

// ------------------------------------------------ phase B body: GN apply + T
__device__ __forceinline__ void gn_apply_body(int n0t, int c0t, int b, int tid,
                                              const float* x, const float* gw,
                                              const float* gb, const float2* stats,
                                              u16* xnT, u16* smem) {
  u16 (*ls)[72] = (u16(*)[72])smem;             // [c][n], pad 72
  const int c0 = c0t * 64, n0 = n0t * 64;
#pragma unroll
  for (int r = 0; r < 4; ++r) {
    const int cc = (tid >> 4) + r * 16;
    const int nn = (tid & 15) * 4;
    const int c = c0 + cc;
    const float2 st = stats[b * 32 + (c >> 3)];
    const float wv = gw[c] * st.y;
    const float bv = gb[c] - st.x * wv;
    float4 u = *(const float4*)(x + ((size_t)b * CCH + c) * NSP + n0 + nn);
    ushort4 o;
    o.x = f2bf(u.x * wv + bv);
    o.y = f2bf(u.y * wv + bv);
    o.z = f2bf(u.z * wv + bv);
    o.w = f2bf(u.w * wv + bv);
    *(ushort4*)&ls[cc][nn] = o;
  }
  __syncthreads();
#pragma unroll
  for (int p = 0; p < 2; ++p) {
    const int idx = tid + p * 256;              // 0..511
    const int nn = idx >> 3;
    const int cb = (idx & 7) * 8;
    u16 tmp[8];
#pragma unroll
    for (int j = 0; j < 8; ++j) tmp[j] = ls[cb + j][nn];
    *(uint4*)(xnT + ((size_t)b * NSP + n0 + nn) * CCH + c0 + cb) = *(uint4*)tmp;
  }
}

// ------------------------------------------------ MFMA GEMM body, BK=64
// C[b][m][n] = sum_c A[m][c]*Bt[b][n][c]; A bf16 MxK(K=256), Bt bf16 NxK.
template <int OUTF32>
__device__ __forceinline__ void gemm_body(const u16* A, const u16* Bt,
                                          const float* bias, void* Cm, int M,
                                          int aBatch, long btStride, int ldc,
                                          int n0, int m0, int bz,
                                          int tid, u16* smem) {
  const int wave = tid >> 6, lane = tid & 63;
  const u16* Ab = A + (size_t)bz * aBatch;
  const u16* Bb = Bt + (size_t)bz * btStride;

  const int lrow = lane >> 3;                   // 0..7: row within 8-row group
  const int kcl  = ((lane & 7) ^ lrow) * 8;     // swizzled k element offset
  const u16* pA[4]; const u16* pB[4];
#pragma unroll
  for (int j = 0; j < 4; ++j) {
    const int row = j * 32 + wave * 8 + lrow;
    pA[j] = Ab + (size_t)(m0 + row) * CCH + kcl;
    pB[j] = Bb + (size_t)(n0 + row) * CCH + kcl;
  }
  u16* lA = smem;                               // 16 KB
  u16* lB = smem + 8192;                        // 16 KB

  const int wm = wave >> 1, wn = wave & 1;
  f32x4 acc[4][4];
#pragma unroll
  for (int i = 0; i < 4; ++i)
#pragma unroll
    for (int j = 0; j < 4; ++j) acc[i][j] = (f32x4){0.f, 0.f, 0.f, 0.f};

  for (int it = 0; it < 4; ++it) {              // K = 256, BK = 64
#pragma unroll
    for (int j = 0; j < 4; ++j) {
      __builtin_amdgcn_global_load_lds(GLB(pA[j]), LDSP(lA + (j * 256 + wave * 64) * 8), 16, 0, 0);
      __builtin_amdgcn_global_load_lds(GLB(pB[j]), LDSP(lB + (j * 256 + wave * 64) * 8), 16, 0, 0);
      pA[j] += 64; pB[j] += 64;
    }
    __syncthreads();
#pragma unroll
    for (int w = 0; w < 2; ++w) {               // two 32-k windows
      const int kcf = w * 4 + (lane >> 4);
      short8 af[4], bfr[4];
#pragma unroll
      for (int mt = 0; mt < 4; ++mt) {
        const int row = wm * 64 + mt * 16 + (lane & 15);
        af[mt] = *(const short8*)&lA[(row * 8 + (kcf ^ (row & 7))) * 8];
      }
#pragma unroll
      for (int nt = 0; nt < 4; ++nt) {
        const int row = wn * 64 + nt * 16 + (lane & 15);
        bfr[nt] = *(const short8*)&lB[(row * 8 + (kcf ^ (row & 7))) * 8];
      }
#pragma unroll
      for (int mt = 0; mt < 4; ++mt)
#pragma unroll
        for (int nt = 0; nt < 4; ++nt)
          acc[mt][nt] = __builtin_amdgcn_mfma_f32_16x16x32_bf16(af[mt], bfr[nt], acc[mt][nt], 0, 0, 0);
    }
    __syncthreads();
  }

  // epilogue: C/D frag col=lane&15, row=(lane>>4)*4+reg
  if (!OUTF32) {
    u16* cl = smem;                             // [128][136] u16 (34816 B)
#pragma unroll
    for (int mt = 0; mt < 4; ++mt)
#pragma unroll
      for (int nt = 0; nt < 4; ++nt)
#pragma unroll
        for (int r = 0; r < 4; ++r) {
          const int row = wm * 64 + mt * 16 + (lane >> 4) * 4 + r;
          const int col = wn * 64 + nt * 16 + (lane & 15);
          cl[row * 136 + col] = f2bf(acc[mt][nt][r]);
        }
    __syncthreads();
    u16* C = (u16*)Cm + (size_t)bz * (size_t)M * ldc;
#pragma unroll
    for (int j = 0; j < 8; ++j) {
      const int idx = tid + j * 256;            // 0..2047
      const int row = idx >> 4, chunk = idx & 15;
      *(uint4*)(C + (size_t)(m0 + row) * ldc + n0 + chunk * 8) =
          *(const uint4*)&cl[row * 136 + chunk * 8];
    }
  } else {
    float* clf = (float*)smem;                  // [64][132] fp32 per pass (33792 B)
    float* C = (float*)Cm + (size_t)bz * (size_t)M * ldc;
#pragma unroll
    for (int pass = 0; pass < 2; ++pass) {
      if (wm == pass) {
#pragma unroll
        for (int mt = 0; mt < 4; ++mt)
#pragma unroll
          for (int nt = 0; nt < 4; ++nt)
#pragma unroll
            for (int r = 0; r < 4; ++r) {
              const int rl = mt * 16 + (lane >> 4) * 4 + r;   // 0..63
              const int col = wn * 64 + nt * 16 + (lane & 15);
              clf[rl * 132 + col] = acc[mt][nt][r] + bias[m0 + pass * 64 + rl];
            }
      }
      __syncthreads();
#pragma unroll
      for (int j = 0; j < 8; ++j) {
        const int idx = tid + j * 256;          // 0..2047
        const int row = idx >> 5, chunk = idx & 31;
        *(float4*)(C + (size_t)(m0 + pass * 64 + row) * ldc + n0 + chunk * 4) =
            *(const float4*)&clf[row * 132 + chunk * 4];
      }
      __syncthreads();
    }
  }
}

// ------------------------------------------------ phase C body: K/V GEMM + att
__device__ __forceinline__ void kv_att_body(int nblk, int hg, int b, int tid,
                                            const u16* A, const u16* Bt,
                                            float* att4, u16* smem) {
  const int wave = tid >> 6, lane = tid & 63;
  const int n0 = nblk * 128;
  const u16* Bb = Bt + (size_t)b * (size_t)NSP * CCH;

  const int lrow = lane >> 3;                   // 0..7
  const int kcl  = ((lane & 7) ^ lrow) * 8;     // swizzled k element offset
  const u16* pA[4]; const u16* pB[4];
#pragma unroll
  for (int j = 0; j < 4; ++j) {
    // local row j*32+wave*8+lrow: [0,64)=K rows, [64,128)=V rows of head pair hg
    const int arow = 256 + (j >> 1) * 256 + hg * 64 + (j & 1) * 32 + wave * 8 + lrow;
    pA[j] = A  + (size_t)arow * CCH + kcl;
    pB[j] = Bb + (size_t)(n0 + j * 32 + wave * 8 + lrow) * CCH + kcl;
  }
  u16* lA = smem;                               // 16 KB
  u16* lB = smem + 8192;                        // 16 KB

  const int wm = wave >> 1, wn = wave & 1;
  f32x4 acc[4][4];
#pragma unroll
  for (int i = 0; i < 4; ++i)
#pragma unroll
    for (int j = 0; j < 4; ++j) acc[i][j] = (f32x4){0.f, 0.f, 0.f, 0.f};

  for (int it = 0; it < 4; ++it) {              // K = 256, BK = 64
#pragma unroll
    for (int j = 0; j < 4; ++j) {
      __builtin_amdgcn_global_load_lds(GLB(pA[j]), LDSP(lA + (j * 256 + wave * 64) * 8), 16, 0, 0);
      __builtin_amdgcn_global_load_lds(GLB(pB[j]), LDSP(lB + (j * 256 + wave * 64) * 8), 16, 0, 0);
      pA[j] += 64; pB[j] += 64;
    }
    __syncthreads();
#pragma unroll
    for (int w = 0; w < 2; ++w) {
      const int kcf = w * 4 + (lane >> 4);
      short8 af[4], bfr[4];
#pragma unroll
      for (int mt = 0; mt < 4; ++mt) {
        const int row = wm * 64 + mt * 16 + (lane & 15);
        af[mt] = *(const short8*)&lA[(row * 8 + (kcf ^ (row & 7))) * 8];
      }
#pragma unroll
      for (int nt = 0; nt < 4; ++nt) {
        const int row = wn * 64 + nt * 16 + (lane & 15);
        bfr[nt] = *(const short8*)&lB[(row * 8 + (kcf ^ (row & 7))) * 8];
      }
#pragma unroll
      for (int mt = 0; mt < 4; ++mt)
#pragma unroll
        for (int nt = 0; nt < 4; ++nt)
          acc[mt][nt] = __builtin_amdgcn_mfma_f32_16x16x32_bf16(af[mt], bfr[nt], acc[mt][nt], 0, 0, 0);
    }
    __syncthreads();
  }

  // epilogue -> clK (exp'ed K rows) / clV, [64][136] each
  u16* clK = smem;                              // bytes [0, 17408)
  u16* clV = smem + 8704;                       // bytes [17408, 34816)
  {
    const int rbase = (lane >> 4) * 4;
    if (wm == 0) {                              // rows 0..63 = K
#pragma unroll
      for (int mt = 0; mt < 4; ++mt)
#pragma unroll
        for (int nt = 0; nt < 4; ++nt)
#pragma unroll
          for (int r = 0; r < 4; ++r) {
            const int row = mt * 16 + rbase + r;
            const int col = wn * 64 + nt * 16 + (lane & 15);
            clK[row * 136 + col] = f2bf(__expf(acc[mt][nt][r]));
          }
    } else {                                    // rows 64..127 = V
#pragma unroll
      for (int mt = 0; mt < 4; ++mt)
#pragma unroll
        for (int nt = 0; nt < 4; ++nt)
#pragma unroll
          for (int r = 0; r < 4; ++r) {
            const int row = mt * 16 + rbase + r;
            const int col = wn * 64 + nt * 16 + (lane & 15);
            clV[row * 136 + col] = f2bf(acc[mt][nt][r]);
          }
    }
  }
  __syncthreads();                              // clK + clV visible to all waves

  // att phase: wave = (head hh in pair, n-half)
  const int hh = wave >> 1, nhalf = wave & 1;
  const int bh = b * 8 + hg * 2 + hh;
  f32x4 a2[2][2], al[2];
#pragma unroll
  for (int i = 0; i < 2; ++i) {
    al[i] = (f32x4){0.f, 0.f, 0.f, 0.f};
#pragma unroll
    for (int j = 0; j < 2; ++j) a2[i][j] = (f32x4){0.f, 0.f, 0.f, 0.f};
  }
  short8 ones;
#pragma unroll
  for (int j = 0; j < 8; ++j) ones[j] = (short)0x3F80;   // bf16 1.0

  const int rr = lane & 15, cc8 = (lane >> 4) * 8;
#pragma unroll
  for (int c = 0; c < 2; ++c) {                 // 2 chunks of 32 n per wave
    const int n = (nhalf * 2 + c) * 32 + cc8;
    short8 ek0 = *(const short8*)&clK[(hh * 32 + rr) * 136 + n];
    short8 ek1 = *(const short8*)&clK[(hh * 32 + 16 + rr) * 136 + n];
    short8 v0  = *(const short8*)&clV[(hh * 32 + rr) * 136 + n];
    short8 v1  = *(const short8*)&clV[(hh * 32 + 16 + rr) * 136 + n];
    a2[0][0] = __builtin_amdgcn_mfma_f32_16x16x32_bf16(ek0, v0, a2[0][0], 0, 0, 0);
    a2[0][1] = __builtin_amdgcn_mfma_f32_16x16x32_bf16(ek0, v1, a2[0][1], 0, 0, 0);
    a2[1][0] = __builtin_amdgcn_mfma_f32_16x16x32_bf16(ek1, v0, a2[1][0], 0, 0, 0);
    a2[1][1] = __builtin_amdgcn_mfma_f32_16x16x32_bf16(ek1, v1, a2[1][1], 0, 0, 0);
    al[0]    = __builtin_amdgcn_mfma_f32_16x16x32_bf16(ek0, ones, al[0], 0, 0, 0);
    al[1]    = __builtin_amdgcn_mfma_f32_16x16x32_bf16(ek1, ones, al[1], 0, 0, 0);
  }
  __syncthreads();                              // done reading clK/clV

  // pair-reduce the two n-half waves of each head in LDS, then atomicAdd
  float* red  = (float*)smem;                   // [2][32][34] f32 (8704 B)
  float* redl = red + 2176;                     // [2][32]
  const int dq = (lane >> 4) * 4;
  if (nhalf == 1) {
#pragma unroll
    for (int dh = 0; dh < 2; ++dh) {
#pragma unroll
      for (int eh = 0; eh < 2; ++eh)
#pragma unroll
        for (int j = 0; j < 4; ++j)
          red[hh * 1088 + (dh * 16 + dq + j) * 34 + eh * 16 + rr] = a2[dh][eh][j];
      if (rr == 0)
#pragma unroll
        for (int j = 0; j < 4; ++j) redl[hh * 32 + dh * 16 + dq + j] = al[dh][j];
    }
  }
  __syncthreads();
  if (nhalf == 0) {
    float* ap = att4 + (size_t)bh * 1056;
#pragma unroll
    for (int dh = 0; dh < 2; ++dh) {
#pragma unroll
      for (int eh = 0; eh < 2; ++eh)
#pragma unroll
        for (int j = 0; j < 4; ++j) {
          const int d = dh * 16 + dq + j, e = eh * 16 + rr;
          atomicAdd(&ap[d * 32 + e], a2[dh][eh][j] + red[hh * 1088 + d * 34 + e]);
        }
      if (rr == 0)
#pragma unroll
        for (int j = 0; j < 4; ++j) {
          const int d = dh * 16 + dq + j;
          atomicAdd(&ap[1024 + d], al[dh][j] + redl[hh * 32 + d]);
        }
    }
  }
}

// ------------------------------------------------ phase D1 body: W2 = wp @ blockdiag(att/l)
__device__ __forceinline__ void w2_body(int blk, int tid, const u16* wp_bf,
                                        const float* att4, u16* W2) {
  const int b = blk >> 4;
  const int o0 = (blk & 15) * 16;
  const int h = tid >> 5, d = tid & 31;
  const float* ap = att4 + ((size_t)b * 8 + h) * 1056;
  const float linv = 1.f / ap[1024 + d];
  float as[32];
#pragma unroll
  for (int e = 0; e < 32; ++e) as[e] = ap[d * 32 + e] * linv;
  u16* w2p = W2 + (size_t)b * 65536;
  for (int oi = 0; oi < 16; ++oi) {
    const int o = o0 + oi;
    const uint4* wr = (const uint4*)(wp_bf + o * 256 + h * 32);
    float acc = 0.f;
#pragma unroll
    for (int j = 0; j < 4; ++j) {
      uint4 u = wr[j];
      const u16* w8 = (const u16*)&u;
#pragma unroll
      for (int t = 0; t < 8; ++t) acc += bf2f(w8[t]) * as[j * 8 + t];
    }
    w2p[o * 256 + tid] = f2bf(acc);             // coalesced u16 row writes
  }
}

// ================================================ the dataflow kernel
// Task order (in-order claim; deps only point to lower-indexed tasks):
//   [0,784)      prep: stats(512, signals bstat[b]) / convw(256, cw) / wqt(16, wqtc)
//   [784,4880)   apply (waits bstat[b]==32; signals anflag[b][n0t>>1], target 8)
//   [4880,6928)  kv_att (waits cw==256, anflag[b][nblk]==8; signals attdone[b])
//   [6928,7184)  w2 (waits cw==256, attdone[b]==128; signals w2done[b])
//   [7184,7248)  w3 gemm (waits wqtc==16, w2done[b]==16; signals w3done[b])
//   [7248,8272)  final gemm (waits w3done[b]==4, anflag[b][n]==8)
// ctrl ints: [0]=next [1]=cw [2]=wqtc [3..18]=bstat [19..34]=attdone
//            [35..50]=w2done [51..66]=w3done [67..578]=anflag[16][32]
#define T_PREP  784
#define T_APPLY 4880
#define T_KV    6928
#define T_W2    7184
#define T_W3    7248
#define T_END   8272

__global__ __launch_bounds__(256, 4) void fused_df(
    const float* __restrict__ x, const float* __restrict__ gn_w,
    const float* __restrict__ gn_b, const float* __restrict__ w_qkv,
    const float* __restrict__ w_proj, const float* __restrict__ b_proj,
    float* __restrict__ out, u16* __restrict__ xnT, u16* __restrict__ wbf,
    u16* __restrict__ wqT, u16* __restrict__ W2, u16* __restrict__ W3,
    float* __restrict__ att4, float2* __restrict__ stats, int* __restrict__ ctrl) {
  __shared__ __align__(16) u16 smem[17408];     // 34816 B
  __shared__ int curtask;
  const int tid = threadIdx.x;
  const u16* wq_bf = wbf;
  const u16* wp_bf = wbf + 196608;

  while (true) {
    __syncthreads();                            // protect curtask + smem reuse
    if (tid == 0) curtask = atomicAdd(&ctrl[0], 1);
    __syncthreads();
    const int t = curtask;
    if (t >= T_END) break;

    if (t < T_PREP) {
      prep_body(t, tid, x, w_qkv, w_proj, stats, att4, wbf, wqT, smem);
      if (t < 512)      signal(&ctrl[3 + (t >> 5)], tid);
      else if (t < 768) signal(&ctrl[1], tid);
      else              signal(&ctrl[2], tid);
    } else if (t < T_APPLY) {
      const int j = t - T_PREP;
      const int b = j >> 8;
      wait_ge(&ctrl[3 + b], 32, tid);
      gn_apply_body(j & 63, (j >> 6) & 3, b, tid, x, gn_w, gn_b, stats, xnT, smem);
      signal(&ctrl[67 + b * 32 + ((j & 63) >> 1)], tid);
    } else if (t < T_KV) {
      const int k = t - T_APPLY;
      const int b = k >> 7, nblk = k & 31, hg = (k >> 5) & 3;
      wait_ge(&ctrl[1], 256, tid);
      wait_ge(&ctrl[67 + b * 32 + nblk], 8, tid);
      kv_att_body(nblk, hg, b, tid, wq_bf, xnT, att4, smem);
      signal(&ctrl[19 + b], tid);
    } else if (t < T_W2) {
      const int w = t - T_KV;
      const int b = w >> 4;
      wait_ge(&ctrl[1], 256, tid);
      wait_ge(&ctrl[19 + b], 128, tid);
      w2_body(w, tid, wp_bf, att4, W2);
      signal(&ctrl[35 + b], tid);
    } else if (t < T_W3) {
      const int v = t - T_W2;
      const int b = v >> 2;
      wait_ge(&ctrl[2], 16, tid);
      wait_ge(&ctrl[35 + b], 16, tid);
      gemm_body<0>(W2, wqT, nullptr, W3, CCH, 65536, 0L, CCH,
                   (v & 1) * 128, ((v >> 1) & 1) * 128, b, tid, smem);
      signal(&ctrl[51 + b], tid);
    } else {
      const int f = t - T_W3;
      const int b = f >> 6, n = f & 31, m = (f >> 5) & 1;
      wait_ge(&ctrl[51 + b], 4, tid);
      wait_ge(&ctrl[67 + b * 32 + n], 8, tid);
      gemm_body<1>(W3, xnT, b_proj, out, CCH, 65536, (long)NSP * CCH, NSP,
                   n * 128, m * 128, b, tid, smem);
    }
  }
}

// ------------------------------------------------ launch
extern "C" void kernel_launch(void* const* d_in, const int* in_sizes, int n_in,
                              void* d_out, int out_size, void* d_ws, size_t ws_size,
                              hipStream_t stream) {
  const float* x      = (const float*)d_in[0];
  const float* gn_w   = (const float*)d_in[1];
  const float* gn_b   = (const float*)d_in[2];
  const float* w_qkv  = (const float*)d_in[3];
  const float* w_proj = (const float*)d_in[4];
  const float* b_proj = (const float*)d_in[5];
  float* out = (float*)d_out;

  char* ws = (char*)d_ws;
  u16*    xnT   = (u16*)ws;                                 // 32 MiB [b][n][c]
  u16*    wbf   = (u16*)(ws + 33554432ull);                 // 512 KiB (wq + wp bf16)
  u16*    wqT   = (u16*)(ws + 34078720ull);                 // 128 KiB (Wq_q^T [c][d])
  u16*    W2    = (u16*)(ws + 34209792ull);                 // 2 MiB [b][256][256]
  u16*    W3    = (u16*)(ws + 36306944ull);                 // 2 MiB [b][256][256]
  float*  att4  = (float*)(ws + 38404096ull);               // 540672 B
  float2* stats = (float2*)(ws + 38944768ull);              // 4 KiB
  int*    ctrl  = (int*)(ws + 38948864ull);                 // 4 KiB counters

  hipMemsetAsync(ctrl, 0, 4096, stream);                    // graph-capturable
  fused_df<<<1024, 256, 0, stream>>>(x, gn_w, gn_b, w_qkv, w_proj, b_proj,
                                     out, xnT, wbf, wqT, W2, W3, att4, stats,
                                     ctrl);
}

// Round 9
// 214.252 us; speedup vs baseline: 7.5879x; 7.5879x over previous
//
#include <hip/hip_runtime.h>
#include <stdint.h>

// x (16,256,64,64) fp32; 32 groups; 8 heads; head dim 32. All I/O fp32.
// Intermediates bf16. Softmax folded: att = diag(1/l) * sum_n exp(k) v.
// R7: att-output folds into w_proj: W2_b = wp @ blockdiag(att/l).
// R9: Q never materialized: out = (W2_b @ Wq_q) @ xn  (W3 = W2@Wq_q per batch).
// R10: kv_att single-pass 128x128 (64 K + 64 V rows); launches merged (6 total).
// R13/R14 post-mortem: single-kernel fusion (grid.sync / dataflow counters) is
//   architecturally wrong on gfx950 — agent/device-scope release/acquire lower
//   to whole-L2 writeback/invalidate per op (non-coherent per-XCD L2s), 5-7x
//   slowdown + 80MB overfetch. Kernel boundaries do that flush ONCE per phase.
// R15: 6 -> 5 launches the legal way: w2+w3 merged algebraically. w23_kernel
//   computes W3 = wp @ blockdiag(att/l) @ Wq_q per 128x128 tile: as->LDS,
//   W2-tile via MFMA (A-frags direct from global wp), plain LDS A-tile
//   [128][264], then the proven BK=64 loop with A from LDS + staged wqT.
#define BATCH 16
#define CCH   256
#define NSP   4096

typedef unsigned short u16;
typedef short  short8 __attribute__((ext_vector_type(8)));   // 8 bf16 (4 VGPRs)
typedef float  f32x4  __attribute__((ext_vector_type(4)));

__device__ __forceinline__ float bf2f(u16 h) {
  union { unsigned int u; float f; } x; x.u = ((unsigned int)h) << 16; return x.f;
}
__device__ __forceinline__ u16 f2bf(float f) {
  union { float f; unsigned int u; } x; x.f = f;
  unsigned int r = 0x7fffu + ((x.u >> 16) & 1u);
  return (u16)((x.u + r) >> 16);
}

#define GLB(p) ((__attribute__((address_space(1))) void*)(p))
#define LDSP(p) ((__attribute__((address_space(3))) void*)(p))

// ------------------------------------------------ phase A: GN stats + att4 zero
// + weights fp32->bf16 + wqT transpose. blk<512: stats; 512..767: convw; 768..783: wqT.
__global__ __launch_bounds__(256) void prep_kernel(const float* __restrict__ x,
                                                   const float* __restrict__ wq,
                                                   const float* __restrict__ wp,
                                                   float2* __restrict__ stats,
                                                   float* __restrict__ att4,
                                                   u16* __restrict__ wbf,
                                                   u16* __restrict__ wqT) {
  __shared__ float red[8];
  __shared__ u16 ls[64][72];
  const int blk = blockIdx.x, tid = threadIdx.x;
  if (blk < 512) {
    {
      float* az = att4 + (size_t)blk * 264;     // zero 128*1056 over 512 blocks
      for (int i = tid; i < 264; i += 256) az[i] = 0.f;
    }
    const float4* xv = (const float4*)(x + (size_t)blk * 32768);
    float s = 0.f, ss = 0.f;
    for (int i = tid; i < 8192; i += 256) {
      float4 u = xv[i];
      s  += u.x + u.y + u.z + u.w;
      ss += u.x * u.x + u.y * u.y + u.z * u.z + u.w * u.w;
    }
#pragma unroll
    for (int off = 32; off > 0; off >>= 1) {
      s  += __shfl_down(s, off);
      ss += __shfl_down(ss, off);
    }
    const int wave = tid >> 6, lane = tid & 63;
    if (lane == 0) { red[wave * 2] = s; red[wave * 2 + 1] = ss; }
    __syncthreads();
    if (tid == 0) {
      const float S  = red[0] + red[2] + red[4] + red[6];
      const float SS = red[1] + red[3] + red[5] + red[7];
      const float mean = S * (1.f / 32768.f);
      const float var  = SS * (1.f / 32768.f) - mean * mean;
      stats[blk] = make_float2(mean, rsqrtf(var + 1e-5f));
    }
  } else if (blk < 768) {
    const int i = ((blk - 512) * 256 + tid) * 4;
    float4 v = (i < 196608) ? *(const float4*)(wq + i)
                            : *(const float4*)(wp + (i - 196608));
    ushort4 o;
    o.x = f2bf(v.x); o.y = f2bf(v.y); o.z = f2bf(v.z); o.w = f2bf(v.w);
    *(ushort4*)(wbf + i) = o;
  } else {
    // wqT[c][d] = bf16(wq[d][c]) for Q rows d<256; 16 blocks of 64x64 tiles
    const int t2 = blk - 768;
    const int c0 = (t2 & 3) * 64, r0 = (t2 >> 2) * 64;
#pragma unroll
    for (int j = 0; j < 4; ++j) {
      const int row = j * 16 + (tid >> 4), col = (tid & 15) * 4;
      float4 u = *(const float4*)(wq + (r0 + row) * 256 + c0 + col);
      ls[row][col]     = f2bf(u.x);
      ls[row][col + 1] = f2bf(u.y);
      ls[row][col + 2] = f2bf(u.z);
      ls[row][col + 3] = f2bf(u.w);
    }
    __syncthreads();
#pragma unroll
    for (int j = 0; j < 2; ++j) {
      const int crow = j * 32 + (tid >> 3), d8 = (tid & 7) * 8;
      u16 tmp[8];
#pragma unroll
      for (int k = 0; k < 8; ++k) tmp[k] = ls[d8 + k][crow];
      *(uint4*)(wqT + (c0 + crow) * 256 + r0 + d8) = *(uint4*)tmp;
    }
  }
}

// ------------------------------------------------ GN apply + transpose
__global__ __launch_bounds__(256) void gn_apply_t(const float* __restrict__ x,
                                                  const float* __restrict__ gw,
                                                  const float* __restrict__ gb,
                                                  const float2* __restrict__ stats,
                                                  u16* __restrict__ xnT) {
  __shared__ u16 ls[64][72];                    // [c][n], pad 72
  const int b = blockIdx.z, c0 = blockIdx.y * 64, n0 = blockIdx.x * 64;
  const int tid = threadIdx.x;
#pragma unroll
  for (int r = 0; r < 4; ++r) {
    const int cc = (tid >> 4) + r * 16;
    const int nn = (tid & 15) * 4;
    const int c = c0 + cc;
    const float2 st = stats[b * 32 + (c >> 3)];
    const float wv = gw[c] * st.y;
    const float bv = gb[c] - st.x * wv;
    float4 u = *(const float4*)(x + ((size_t)b * CCH + c) * NSP + n0 + nn);
    ushort4 o;
    o.x = f2bf(u.x * wv + bv);
    o.y = f2bf(u.y * wv + bv);
    o.z = f2bf(u.z * wv + bv);
    o.w = f2bf(u.w * wv + bv);
    *(ushort4*)&ls[cc][nn] = o;
  }
  __syncthreads();
#pragma unroll
  for (int p = 0; p < 2; ++p) {
    const int idx = tid + p * 256;              // 0..511
    const int nn = idx >> 3;
    const int cb = (idx & 7) * 8;
    u16 tmp[8];
#pragma unroll
    for (int j = 0; j < 8; ++j) tmp[j] = ls[cb + j][nn];
    *(uint4*)(xnT + ((size_t)b * NSP + n0 + nn) * CCH + c0 + cb) = *(uint4*)tmp;
  }
}

// ------------------------------------------------ MFMA GEMM, BK=64 (final gemm)
// C[b][m][n] = sum_c A[m][c]*Bt[b][n][c]; fp32 out + bias; ldc row stride.
__global__ __launch_bounds__(256) void gemm_f32(const u16* __restrict__ A,
                                                const u16* __restrict__ Bt,
                                                const float* __restrict__ bias,
                                                float* __restrict__ Cm, int M,
                                                int aBatch, long btStride, int ldc) {
  __shared__ __align__(16) u16 smem[17408];     // 34816 B
  const int tid = threadIdx.x, wave = tid >> 6, lane = tid & 63;
  const int n0 = blockIdx.x * 128, m0 = blockIdx.y * 128, bz = blockIdx.z;
  const u16* Ab = A + (size_t)bz * aBatch;
  const u16* Bb = Bt + (size_t)bz * btStride;

  const int lrow = lane >> 3;                   // 0..7: row within 8-row group
  const int kcl  = ((lane & 7) ^ lrow) * 8;     // swizzled k element offset
  const u16* pA[4]; const u16* pB[4];
#pragma unroll
  for (int j = 0; j < 4; ++j) {
    const int row = j * 32 + wave * 8 + lrow;
    pA[j] = Ab + (size_t)(m0 + row) * CCH + kcl;
    pB[j] = Bb + (size_t)(n0 + row) * CCH + kcl;
  }
  u16* lA = smem;                               // 16 KB
  u16* lB = smem + 8192;                        // 16 KB

  const int wm = wave >> 1, wn = wave & 1;
  f32x4 acc[4][4];
#pragma unroll
  for (int i = 0; i < 4; ++i)
#pragma unroll
    for (int j = 0; j < 4; ++j) acc[i][j] = (f32x4){0.f, 0.f, 0.f, 0.f};

  for (int it = 0; it < 4; ++it) {              // K = 256, BK = 64
#pragma unroll
    for (int j = 0; j < 4; ++j) {
      __builtin_amdgcn_global_load_lds(GLB(pA[j]), LDSP(lA + (j * 256 + wave * 64) * 8), 16, 0, 0);
      __builtin_amdgcn_global_load_lds(GLB(pB[j]), LDSP(lB + (j * 256 + wave * 64) * 8), 16, 0, 0);
      pA[j] += 64; pB[j] += 64;
    }
    __syncthreads();
#pragma unroll
    for (int w = 0; w < 2; ++w) {               // two 32-k windows
      const int kcf = w * 4 + (lane >> 4);
      short8 af[4], bfr[4];
#pragma unroll
      for (int mt = 0; mt < 4; ++mt) {
        const int row = wm * 64 + mt * 16 + (lane & 15);
        af[mt] = *(const short8*)&lA[(row * 8 + (kcf ^ (row & 7))) * 8];
      }
#pragma unroll
      for (int nt = 0; nt < 4; ++nt) {
        const int row = wn * 64 + nt * 16 + (lane & 15);
        bfr[nt] = *(const short8*)&lB[(row * 8 + (kcf ^ (row & 7))) * 8];
      }
#pragma unroll
      for (int mt = 0; mt < 4; ++mt)
#pragma unroll
        for (int nt = 0; nt < 4; ++nt)
          acc[mt][nt] = __builtin_amdgcn_mfma_f32_16x16x32_bf16(af[mt], bfr[nt], acc[mt][nt], 0, 0, 0);
    }
    __syncthreads();
  }

  // epilogue: fp32 + bias, two passes through LDS
  float* clf = (float*)smem;                    // [64][132] fp32 per pass
  float* C = Cm + (size_t)bz * (size_t)M * ldc;
#pragma unroll
  for (int pass = 0; pass < 2; ++pass) {
    if (wm == pass) {
#pragma unroll
      for (int mt = 0; mt < 4; ++mt)
#pragma unroll
        for (int nt = 0; nt < 4; ++nt)
#pragma unroll
          for (int r = 0; r < 4; ++r) {
            const int rl = mt * 16 + (lane >> 4) * 4 + r;   // 0..63
            const int col = wn * 64 + nt * 16 + (lane & 15);
            clf[rl * 132 + col] = acc[mt][nt][r] + bias[m0 + pass * 64 + rl];
          }
    }
    __syncthreads();
#pragma unroll
    for (int j = 0; j < 8; ++j) {
      const int idx = tid + j * 256;            // 0..2047
      const int row = idx >> 5, chunk = idx & 31;
      *(float4*)(C + (size_t)(m0 + pass * 64 + row) * ldc + n0 + chunk * 4) =
          *(const float4*)&clf[row * 132 + chunk * 4];
    }
    __syncthreads();
  }
}

// ------------------------------------------------ fused K/V GEMM + att reduction
__global__ __launch_bounds__(256, 4) void gemm_kv_att(const u16* __restrict__ A,
                                                      const u16* __restrict__ Bt,
                                                      float* __restrict__ att4) {
  __shared__ __align__(16) u16 smem[17408];     // 34816 B
  const int tid = threadIdx.x, wave = tid >> 6, lane = tid & 63;
  const int n0 = blockIdx.x * 128, hg = blockIdx.y, b = blockIdx.z;
  const u16* Bb = Bt + (size_t)b * (size_t)NSP * CCH;

  const int lrow = lane >> 3;                   // 0..7
  const int kcl  = ((lane & 7) ^ lrow) * 8;     // swizzled k element offset
  const u16* pA[4]; const u16* pB[4];
#pragma unroll
  for (int j = 0; j < 4; ++j) {
    // local row j*32+wave*8+lrow: [0,64)=K rows, [64,128)=V rows of head pair hg
    const int arow = 256 + (j >> 1) * 256 + hg * 64 + (j & 1) * 32 + wave * 8 + lrow;
    pA[j] = A  + (size_t)arow * CCH + kcl;
    pB[j] = Bb + (size_t)(n0 + j * 32 + wave * 8 + lrow) * CCH + kcl;
  }
  u16* lA = smem;                               // 16 KB
  u16* lB = smem + 8192;                        // 16 KB

  const int wm = wave >> 1, wn = wave & 1;
  f32x4 acc[4][4];
#pragma unroll
  for (int i = 0; i < 4; ++i)
#pragma unroll
    for (int j = 0; j < 4; ++j) acc[i][j] = (f32x4){0.f, 0.f, 0.f, 0.f};

  for (int it = 0; it < 4; ++it) {              // K = 256, BK = 64
#pragma unroll
    for (int j = 0; j < 4; ++j) {
      __builtin_amdgcn_global_load_lds(GLB(pA[j]), LDSP(lA + (j * 256 + wave * 64) * 8), 16, 0, 0);
      __builtin_amdgcn_global_load_lds(GLB(pB[j]), LDSP(lB + (j * 256 + wave * 64) * 8), 16, 0, 0);
      pA[j] += 64; pB[j] += 64;
    }
    __syncthreads();
#pragma unroll
    for (int w = 0; w < 2; ++w) {
      const int kcf = w * 4 + (lane >> 4);
      short8 af[4], bfr[4];
#pragma unroll
      for (int mt = 0; mt < 4; ++mt) {
        const int row = wm * 64 + mt * 16 + (lane & 15);
        af[mt] = *(const short8*)&lA[(row * 8 + (kcf ^ (row & 7))) * 8];
      }
#pragma unroll
      for (int nt = 0; nt < 4; ++nt) {
        const int row = wn * 64 + nt * 16 + (lane & 15);
        bfr[nt] = *(const short8*)&lB[(row * 8 + (kcf ^ (row & 7))) * 8];
      }
#pragma unroll
      for (int mt = 0; mt < 4; ++mt)
#pragma unroll
        for (int nt = 0; nt < 4; ++nt)
          acc[mt][nt] = __builtin_amdgcn_mfma_f32_16x16x32_bf16(af[mt], bfr[nt], acc[mt][nt], 0, 0, 0);
    }
    __syncthreads();
  }

  // epilogue -> clK (exp'ed K rows) / clV, [64][136] each
  u16* clK = smem;                              // bytes [0, 17408)
  u16* clV = smem + 8704;                       // bytes [17408, 34816)
  {
    const int rbase = (lane >> 4) * 4;
    if (wm == 0) {                              // rows 0..63 = K
#pragma unroll
      for (int mt = 0; mt < 4; ++mt)
#pragma unroll
        for (int nt = 0; nt < 4; ++nt)
#pragma unroll
          for (int r = 0; r < 4; ++r) {
            const int row = mt * 16 + rbase + r;
            const int col = wn * 64 + nt * 16 + (lane & 15);
            clK[row * 136 + col] = f2bf(__expf(acc[mt][nt][r]));
          }
    } else {                                    // rows 64..127 = V
#pragma unroll
      for (int mt = 0; mt < 4; ++mt)
#pragma unroll
        for (int nt = 0; nt < 4; ++nt)
#pragma unroll
          for (int r = 0; r < 4; ++r) {
            const int row = mt * 16 + rbase + r;
            const int col = wn * 64 + nt * 16 + (lane & 15);
            clV[row * 136 + col] = f2bf(acc[mt][nt][r]);
          }
    }
  }
  __syncthreads();                              // clK + clV visible to all waves

  // att phase: wave = (head hh in pair, n-half)
  const int hh = wave >> 1, nhalf = wave & 1;
  const int bh = b * 8 + hg * 2 + hh;
  f32x4 a2[2][2], al[2];
#pragma unroll
  for (int i = 0; i < 2; ++i) {
    al[i] = (f32x4){0.f, 0.f, 0.f, 0.f};
#pragma unroll
    for (int j = 0; j < 2; ++j) a2[i][j] = (f32x4){0.f, 0.f, 0.f, 0.f};
  }
  short8 ones;
#pragma unroll
  for (int j = 0; j < 8; ++j) ones[j] = (short)0x3F80;   // bf16 1.0

  const int rr = lane & 15, cc8 = (lane >> 4) * 8;
#pragma unroll
  for (int c = 0; c < 2; ++c) {                 // 2 chunks of 32 n per wave
    const int n = (nhalf * 2 + c) * 32 + cc8;
    short8 ek0 = *(const short8*)&clK[(hh * 32 + rr) * 136 + n];
    short8 ek1 = *(const short8*)&clK[(hh * 32 + 16 + rr) * 136 + n];
    short8 v0  = *(const short8*)&clV[(hh * 32 + rr) * 136 + n];
    short8 v1  = *(const short8*)&clV[(hh * 32 + 16 + rr) * 136 + n];
    a2[0][0] = __builtin_amdgcn_mfma_f32_16x16x32_bf16(ek0, v0, a2[0][0], 0, 0, 0);
    a2[0][1] = __builtin_amdgcn_mfma_f32_16x16x32_bf16(ek0, v1, a2[0][1], 0, 0, 0);
    a2[1][0] = __builtin_amdgcn_mfma_f32_16x16x32_bf16(ek1, v0, a2[1][0], 0, 0, 0);
    a2[1][1] = __builtin_amdgcn_mfma_f32_16x16x32_bf16(ek1, v1, a2[1][1], 0, 0, 0);
    al[0]    = __builtin_amdgcn_mfma_f32_16x16x32_bf16(ek0, ones, al[0], 0, 0, 0);
    al[1]    = __builtin_amdgcn_mfma_f32_16x16x32_bf16(ek1, ones, al[1], 0, 0, 0);
  }
  __syncthreads();                              // done reading clK/clV

  // pair-reduce the two n-half waves of each head in LDS, then atomicAdd
  float* red  = (float*)smem;                   // [2][32][34] f32 (8704 B)
  float* redl = red + 2176;                     // [2][32]
  const int dq = (lane >> 4) * 4;
  if (nhalf == 1) {
#pragma unroll
    for (int dh = 0; dh < 2; ++dh) {
#pragma unroll
      for (int eh = 0; eh < 2; ++eh)
#pragma unroll
        for (int j = 0; j < 4; ++j)
          red[hh * 1088 + (dh * 16 + dq + j) * 34 + eh * 16 + rr] = a2[dh][eh][j];
      if (rr == 0)
#pragma unroll
        for (int j = 0; j < 4; ++j) redl[hh * 32 + dh * 16 + dq + j] = al[dh][j];
    }
  }
  __syncthreads();
  if (nhalf == 0) {
    float* ap = att4 + (size_t)bh * 1056;
#pragma unroll
    for (int dh = 0; dh < 2; ++dh) {
#pragma unroll
      for (int eh = 0; eh < 2; ++eh)
#pragma unroll
        for (int j = 0; j < 4; ++j) {
          const int d = dh * 16 + dq + j, e = eh * 16 + rr;
          atomicAdd(&ap[d * 32 + e], a2[dh][eh][j] + red[hh * 1088 + d * 34 + e]);
        }
      if (rr == 0)
#pragma unroll
        for (int j = 0; j < 4; ++j) {
          const int d = dh * 16 + dq + j;
          atomicAdd(&ap[1024 + d], al[dh][j] + redl[hh * 32 + d]);
        }
    }
  }
}

// ------------------------------------------------ w23: W3 = wp @ blockdiag(att/l) @ Wq_q
// 64 blocks = (n0 in {0,128}, m0 in {0,128}, b). LDS map (bytes):
//   [0, 67584)        lA: W2-tile u16 [128][264] (pad 264 -> 2-way banks, free)
//   [67584, 101376)   asb: f32 [8][32][33] = as[h][d][e] (att/l)
//   [101376, 117760)  lB: staged wqT granules (16 KB)
//   epilogue cl u16 [128][136] at byte 67584 (asb/lB dead by then)
__global__ __launch_bounds__(256) void w23_kernel(const u16* __restrict__ wp_bf,
                                                  const u16* __restrict__ wqT,
                                                  const float* __restrict__ att4,
                                                  u16* __restrict__ W3) {
  __shared__ __align__(16) u16 smem[58880];     // 117760 B (64 blocks -> occ moot)
  const int tid = threadIdx.x, wave = tid >> 6, lane = tid & 63;
  const int n0 = blockIdx.x * 128, m0 = blockIdx.y * 128, b = blockIdx.z;

  u16*   lA  = smem;                            // [128][264] u16
  float* asb = (float*)(smem + 33792);          // [8][32][33] f32
  u16*   lB  = smem + 50688;                    // 1024 granules

  // phase 0: as[h][d][e] = att[bh][d][e] / l[bh][d]
  {
    const float* ab = att4 + (size_t)b * 8 * 1056;
    for (int i = tid; i < 8192; i += 256) {
      const int h = i >> 10, d = (i >> 5) & 31, e = i & 31;
      asb[h * 1056 + d * 33 + e] = ab[h * 1056 + d * 32 + e] / ab[h * 1056 + 1024 + d];
    }
  }
  __syncthreads();

  // phase 1: W2-tile via MFMA -> lA. wave handles heads {2*wave, 2*wave+1}.
  // W2[o][h*32+d] = sum_e wp[o][h*32+e] * as[h][d][e]
  // A-frag direct from global wp (row o = lane&15 within m-tile, 8 e-contig at
  // (lane>>4)*8); B-frag from asb (row d, 8 e-contig), cvt to bf16.
  {
    const int r16 = lane & 15, e0 = (lane >> 4) * 8;
#pragma unroll
    for (int hh = 0; hh < 2; ++hh) {
      const int h = wave * 2 + hh;
#pragma unroll
      for (int nt = 0; nt < 2; ++nt) {
        // B-frag for this (h, nt): as[h][nt*16 + r16][e0..e0+8)
        const float* bp = asb + h * 1056 + (nt * 16 + r16) * 33 + e0;
        short8 bfr;
#pragma unroll
        for (int j = 0; j < 8; ++j) bfr[j] = (short)f2bf(bp[j]);
#pragma unroll
        for (int mt = 0; mt < 8; ++mt) {
          const int orow = mt * 16 + r16;
          short8 af = *(const short8*)(wp_bf + (size_t)(m0 + orow) * 256 + h * 32 + e0);
          f32x4 c = __builtin_amdgcn_mfma_f32_16x16x32_bf16(af, bfr, (f32x4){0.f,0.f,0.f,0.f}, 0, 0, 0);
          // C frag: col(lane&15)=d within nt-tile, row=(lane>>4)*4+r = o within mt-tile
#pragma unroll
          for (int r = 0; r < 4; ++r) {
            const int o = mt * 16 + (lane >> 4) * 4 + r;
            const int d2 = h * 32 + nt * 16 + r16;
            lA[o * 264 + d2] = f2bf(c[r]);
          }
        }
      }
    }
  }
  __syncthreads();

  // phase 2: W3 tile = lA(W2) @ wqT^T, BK=64, B staged as usual
  const int lrow = lane >> 3;
  const int kcl  = ((lane & 7) ^ lrow) * 8;
  const u16* pB[4];
#pragma unroll
  for (int j = 0; j < 4; ++j)
    pB[j] = wqT + (size_t)(n0 + j * 32 + wave * 8 + lrow) * 256 + kcl;

  const int wm = wave >> 1, wn = wave & 1;
  f32x4 acc[4][4];
#pragma unroll
  for (int i = 0; i < 4; ++i)
#pragma unroll
    for (int j = 0; j < 4; ++j) acc[i][j] = (f32x4){0.f, 0.f, 0.f, 0.f};

  for (int it = 0; it < 4; ++it) {
#pragma unroll
    for (int j = 0; j < 4; ++j) {
      __builtin_amdgcn_global_load_lds(GLB(pB[j]), LDSP(lB + (j * 256 + wave * 64) * 8), 16, 0, 0);
      pB[j] += 64;
    }
    __syncthreads();
#pragma unroll
    for (int w = 0; w < 2; ++w) {
      const int kcf = w * 4 + (lane >> 4);
      short8 af[4], bfr[4];
#pragma unroll
      for (int mt = 0; mt < 4; ++mt) {
        const int row = wm * 64 + mt * 16 + (lane & 15);
        af[mt] = *(const short8*)&lA[row * 264 + it * 64 + kcf * 8];
      }
#pragma unroll
      for (int nt = 0; nt < 4; ++nt) {
        const int row = wn * 64 + nt * 16 + (lane & 15);
        bfr[nt] = *(const short8*)&lB[(row * 8 + (kcf ^ (row & 7))) * 8];
      }
#pragma unroll
      for (int mt = 0; mt < 4; ++mt)
#pragma unroll
        for (int nt = 0; nt < 4; ++nt)
          acc[mt][nt] = __builtin_amdgcn_mfma_f32_16x16x32_bf16(af[mt], bfr[nt], acc[mt][nt], 0, 0, 0);
    }
    __syncthreads();
  }

  // epilogue: u16 tile at byte 67584, coalesced store to W3 (ldc=256)
  u16* cl = smem + 33792;                       // [128][136] u16
#pragma unroll
  for (int mt = 0; mt < 4; ++mt)
#pragma unroll
    for (int nt = 0; nt < 4; ++nt)
#pragma unroll
      for (int r = 0; r < 4; ++r) {
        const int row = wm * 64 + mt * 16 + (lane >> 4) * 4 + r;
        const int col = wn * 64 + nt * 16 + (lane & 15);
        cl[row * 136 + col] = f2bf(acc[mt][nt][r]);
      }
  __syncthreads();
  u16* C = W3 + (size_t)b * 65536;
#pragma unroll
  for (int j = 0; j < 8; ++j) {
    const int idx = tid + j * 256;              // 0..2047
    const int row = idx >> 4, chunk = idx & 15;
    *(uint4*)(C + (size_t)(m0 + row) * 256 + n0 + chunk * 8) =
        *(const uint4*)&cl[row * 136 + chunk * 8];
  }
}

// ------------------------------------------------ launch (5 kernels)
extern "C" void kernel_launch(void* const* d_in, const int* in_sizes, int n_in,
                              void* d_out, int out_size, void* d_ws, size_t ws_size,
                              hipStream_t stream) {
  const float* x      = (const float*)d_in[0];
  const float* gn_w   = (const float*)d_in[1];
  const float* gn_b   = (const float*)d_in[2];
  const float* w_qkv  = (const float*)d_in[3];
  const float* w_proj = (const float*)d_in[4];
  const float* b_proj = (const float*)d_in[5];
  float* out = (float*)d_out;

  char* ws = (char*)d_ws;
  u16*    xnT   = (u16*)ws;                                 // 32 MiB [b][n][c]
  u16*    wbf   = (u16*)(ws + 33554432ull);                 // 512 KiB (wq + wp bf16)
  u16*    wqT   = (u16*)(ws + 34078720ull);                 // 128 KiB (Wq_q^T [c][d])
  u16*    W3    = (u16*)(ws + 36306944ull);                 // 2 MiB [b][256][256]
  float*  att4  = (float*)(ws + 38404096ull);               // 540672 B
  float2* stats = (float2*)(ws + 38944768ull);              // 4 KiB
  u16* wq_bf = wbf;
  u16* wp_bf = wbf + 196608;

  prep_kernel<<<784, 256, 0, stream>>>(x, w_qkv, w_proj, stats, att4, wbf, wqT);
  gn_apply_t<<<dim3(64, 4, 16), 256, 0, stream>>>(x, gn_w, gn_b, stats, xnT);
  gemm_kv_att<<<dim3(32, 4, 16), 256, 0, stream>>>(wq_bf, xnT, att4);
  w23_kernel<<<dim3(2, 2, 16), 256, 0, stream>>>(wp_bf, wqT, att4, W3);
  gemm_f32<<<dim3(32, 2, 16), 256, 0, stream>>>(W3, xnT, b_proj, out,
                                                CCH, 65536, (long)NSP * CCH, NSP);
}

// Round 11
// 208.688 us; speedup vs baseline: 7.7902x; 1.0267x over previous
//
#include <hip/hip_runtime.h>
#include <stdint.h>

// x (16,256,64,64) fp32; 32 groups; 8 heads; head dim 32. All I/O fp32.
// Intermediates bf16. Softmax folded: att = diag(1/l) * sum_n exp(k) v.
// R7:  att-output folds into w_proj: W2_b = wp @ blockdiag(att/l).
// R9:  Q never materialized: out = (W2_b @ Wq_q) @ xn (W3 = W2@Wq_q per batch).
// R10: kv_att single-pass 128x128 (64 K + 64 V rows).
// R13/14: in-kernel cross-XCD sync is architecturally wrong on gfx950 (L2
//   writeback/inv per agent-scope op); kernel boundaries only.
// R16: GroupNorm FOLDED OUT of the data path (diagonal commutes into A-side):
//   k/v = (Wkv . wv) @ x_raw + dot(Wkv,bv);  out = (W3 D_wv) @ x_raw + bias3,
//   bias3 = W2@qbias + b_proj (computed from the LDS W2-tile in w23).
//   gn_apply deleted; xprep transposes x->bf16 xT while accumulating group
//   stats (shuffle-reduce + atomics); wfold builds wv/bv, A'_kv, q/kv biases.
//   5 launches: xprep -> wfold -> kv_att -> w23 -> final.
// R17: identical to R16 — previous round was a broker/container failure, not a
//   kernel signal; re-submitting for measurement after a full re-audit.
#define BATCH 16
#define CCH   256
#define NSP   4096

typedef unsigned short u16;
typedef short  short8 __attribute__((ext_vector_type(8)));   // 8 bf16 (4 VGPRs)
typedef float  f32x4  __attribute__((ext_vector_type(4)));

__device__ __forceinline__ float bf2f(u16 h) {
  union { unsigned int u; float f; } x; x.u = ((unsigned int)h) << 16; return x.f;
}
__device__ __forceinline__ u16 f2bf(float f) {
  union { float f; unsigned int u; } x; x.f = f;
  unsigned int r = 0x7fffu + ((x.u >> 16) & 1u);
  return (u16)((x.u + r) >> 16);
}

#define GLB(p) ((__attribute__((address_space(1))) void*)(p))
#define LDSP(p) ((__attribute__((address_space(3))) void*)(p))

// ------------------------------------------------ xprep: x -> xT (bf16, raw)
// + group-stat partials + wp fp32->bf16 + wqT transpose + att4 zero.
// blk<4096: transpose+stats; 4096..4159: wp conv; 4160..4175: wqT; 4176..4307: zero att4.
__global__ __launch_bounds__(256) void xprep_kernel(const float* __restrict__ x,
                                                    const float* __restrict__ wq,
                                                    const float* __restrict__ wp,
                                                    u16* __restrict__ xT,
                                                    u16* __restrict__ wpbf,
                                                    u16* __restrict__ wqT,
                                                    float* __restrict__ att4,
                                                    float* __restrict__ gstat) {
  __shared__ u16 ls[64][72];
  const int blk = blockIdx.x, tid = threadIdx.x;
  if (blk < 4096) {
    const int n0 = (blk & 63) * 64, c0 = ((blk >> 6) & 3) * 64, b = blk >> 8;
    const int q = tid >> 4, nn = (tid & 15) * 4;
    float s = 0.f, ss = 0.f;
#pragma unroll
    for (int r = 0; r < 4; ++r) {
      const int cc = q * 4 + r;                 // rows 4q..4q+3: one group per thread
      float4 u = *(const float4*)(x + ((size_t)b * CCH + c0 + cc) * NSP + n0 + nn);
      ushort4 o;
      o.x = f2bf(u.x); o.y = f2bf(u.y); o.z = f2bf(u.z); o.w = f2bf(u.w);
      *(ushort4*)&ls[cc][nn] = o;
      s  += u.x + u.y + u.z + u.w;
      ss += u.x * u.x + u.y * u.y + u.z * u.z + u.w * u.w;
    }
    // 32-lane halves each hold one group (g_loc = q>>1); butterfly within half
#pragma unroll
    for (int m = 16; m >= 1; m >>= 1) {
      s  += __shfl_xor(s, m);
      ss += __shfl_xor(ss, m);
    }
    if ((tid & 31) == 0) {
      const int g = ((blk >> 6) & 3) * 8 + (q >> 1);
      atomicAdd(&gstat[(b * 32 + g) * 2 + 0], s);
      atomicAdd(&gstat[(b * 32 + g) * 2 + 1], ss);
    }
    __syncthreads();
#pragma unroll
    for (int p = 0; p < 2; ++p) {
      const int idx = tid + p * 256;            // 0..511
      const int nnr = idx >> 3;
      const int cb = (idx & 7) * 8;
      u16 tmp[8];
#pragma unroll
      for (int j = 0; j < 8; ++j) tmp[j] = ls[cb + j][nnr];
      *(uint4*)(xT + ((size_t)b * NSP + n0 + nnr) * CCH + c0 + cb) = *(uint4*)tmp;
    }
  } else if (blk < 4160) {
    const int i = ((blk - 4096) * 256 + tid) * 4;       // wp: 65536 floats
    float4 v = *(const float4*)(wp + i);
    ushort4 o;
    o.x = f2bf(v.x); o.y = f2bf(v.y); o.z = f2bf(v.z); o.w = f2bf(v.w);
    *(ushort4*)(wpbf + i) = o;
  } else if (blk < 4176) {
    // wqT[c][d] = bf16(wq[d][c]) for Q rows d<256; 16 blocks of 64x64 tiles
    const int t2 = blk - 4160;
    const int c0 = (t2 & 3) * 64, r0 = (t2 >> 2) * 64;
#pragma unroll
    for (int j = 0; j < 4; ++j) {
      const int row = j * 16 + (tid >> 4), col = (tid & 15) * 4;
      float4 u = *(const float4*)(wq + (r0 + row) * 256 + c0 + col);
      ls[row][col]     = f2bf(u.x);
      ls[row][col + 1] = f2bf(u.y);
      ls[row][col + 2] = f2bf(u.z);
      ls[row][col + 3] = f2bf(u.w);
    }
    __syncthreads();
#pragma unroll
    for (int j = 0; j < 2; ++j) {
      const int crow = j * 32 + (tid >> 3), d8 = (tid & 7) * 8;
      u16 tmp[8];
#pragma unroll
      for (int k = 0; k < 8; ++k) tmp[k] = ls[d8 + k][crow];
      *(uint4*)(wqT + (c0 + crow) * 256 + r0 + d8) = *(uint4*)tmp;
    }
  } else {
    // zero att4: 132 blocks * 1024 floats = 135168
    float4 z = {0.f, 0.f, 0.f, 0.f};
    *(float4*)(att4 + (size_t)(blk - 4176) * 1024 + tid * 4) = z;
  }
}

// ------------------------------------------------ wfold: stats -> wv/bv; build
// A'_kv[b][r][c] = bf16(Wkv[r][c]*wv[c]); kvbias/qbias = dot(W,bv); wvv_g.
// grid (24 row-tiles of 32, 16 b).
__global__ __launch_bounds__(256) void wfold_kernel(const float* __restrict__ wqkv,
                                                    const float* __restrict__ gw,
                                                    const float* __restrict__ gb,
                                                    const float* __restrict__ gstat,
                                                    u16* __restrict__ Akv,
                                                    float* __restrict__ wvv_g,
                                                    float* __restrict__ qbias,
                                                    float* __restrict__ kvbias) {
  __shared__ float wvv[256], bvv[256];
  const int rt = blockIdx.x, b = blockIdx.y;
  const int tid = threadIdx.x;
  if (tid < 32) {
    const float gs  = gstat[(b * 32 + tid) * 2 + 0];
    const float gss = gstat[(b * 32 + tid) * 2 + 1];
    const float mean = gs * (1.f / 32768.f);
    const float var  = gss * (1.f / 32768.f) - mean * mean;
    const float rs = rsqrtf(var + 1e-5f);
#pragma unroll
    for (int j = 0; j < 8; ++j) {
      const int c = tid * 8 + j;
      const float wv = gw[c] * rs;
      wvv[c] = wv;
      bvv[c] = gb[c] - mean * wv;
      if (rt == 0) wvv_g[b * 256 + c] = wv;
    }
  }
  __syncthreads();
  const int row_l = tid >> 3, k = tid & 7, c0 = k * 32;
  const int grow = rt * 32 + row_l;             // global qkv row 0..767
  const float* wr = wqkv + (size_t)grow * 256 + c0;
  float acc = 0.f;
  u16 ob[32];
#pragma unroll
  for (int jj = 0; jj < 8; ++jj) {
    float4 u = *(const float4*)(wr + jj * 4);
    const float* uf = (const float*)&u;
#pragma unroll
    for (int t = 0; t < 4; ++t) {
      const int c = c0 + jj * 4 + t;
      acc += uf[t] * bvv[c];
      ob[jj * 4 + t] = f2bf(uf[t] * wvv[c]);
    }
  }
#pragma unroll
  for (int m = 4; m >= 1; m >>= 1) acc += __shfl_xor(acc, m);
  if (grow < 256) {
    if (k == 0) qbias[b * 256 + grow] = acc;
  } else {
    u16* dst = Akv + ((size_t)b * 512 + grow - 256) * 256 + c0;
#pragma unroll
    for (int j = 0; j < 4; ++j) ((uint4*)dst)[j] = ((const uint4*)ob)[j];
    if (k == 0) kvbias[b * 512 + grow - 256] = acc;
  }
}

// ------------------------------------------------ fused K/V GEMM + att reduction
// A = A'_kv (per-batch, rows [0,256)=K, [256,512)=V), B = xT raw.
// Epilogue adds kvbias row-constant, exp for K. att phase unchanged.
__global__ __launch_bounds__(256, 4) void gemm_kv_att(const u16* __restrict__ Akv,
                                                      const u16* __restrict__ Bt,
                                                      const float* __restrict__ kvbias,
                                                      float* __restrict__ att4) {
  __shared__ __align__(16) u16 smem[17408];     // 34816 B
  const int tid = threadIdx.x, wave = tid >> 6, lane = tid & 63;
  const int n0 = blockIdx.x * 128, hg = blockIdx.y, b = blockIdx.z;
  const u16* Ab = Akv + (size_t)b * 512 * 256;
  const u16* Bb = Bt + (size_t)b * (size_t)NSP * CCH;

  const int lrow = lane >> 3;                   // 0..7
  const int kcl  = ((lane & 7) ^ lrow) * 8;     // swizzled k element offset
  const u16* pA[4]; const u16* pB[4];
#pragma unroll
  for (int j = 0; j < 4; ++j) {
    // local m row j*32+wave*8+lrow: [0,64)=K rows, [64,128)=V rows of head pair hg
    const int arow = (j >> 1) * 256 + hg * 64 + (j & 1) * 32 + wave * 8 + lrow;
    pA[j] = Ab + (size_t)arow * CCH + kcl;
    pB[j] = Bb + (size_t)(n0 + j * 32 + wave * 8 + lrow) * CCH + kcl;
  }
  u16* lA = smem;                               // 16 KB
  u16* lB = smem + 8192;                        // 16 KB

  const int wm = wave >> 1, wn = wave & 1;
  f32x4 acc[4][4];
#pragma unroll
  for (int i = 0; i < 4; ++i)
#pragma unroll
    for (int j = 0; j < 4; ++j) acc[i][j] = (f32x4){0.f, 0.f, 0.f, 0.f};

  for (int it = 0; it < 4; ++it) {              // K = 256, BK = 64
#pragma unroll
    for (int j = 0; j < 4; ++j) {
      __builtin_amdgcn_global_load_lds(GLB(pA[j]), LDSP(lA + (j * 256 + wave * 64) * 8), 16, 0, 0);
      __builtin_amdgcn_global_load_lds(GLB(pB[j]), LDSP(lB + (j * 256 + wave * 64) * 8), 16, 0, 0);
      pA[j] += 64; pB[j] += 64;
    }
    __syncthreads();
#pragma unroll
    for (int w = 0; w < 2; ++w) {
      const int kcf = w * 4 + (lane >> 4);
      short8 af[4], bfr[4];
#pragma unroll
      for (int mt = 0; mt < 4; ++mt) {
        const int row = wm * 64 + mt * 16 + (lane & 15);
        af[mt] = *(const short8*)&lA[(row * 8 + (kcf ^ (row & 7))) * 8];
      }
#pragma unroll
      for (int nt = 0; nt < 4; ++nt) {
        const int row = wn * 64 + nt * 16 + (lane & 15);
        bfr[nt] = *(const short8*)&lB[(row * 8 + (kcf ^ (row & 7))) * 8];
      }
#pragma unroll
      for (int mt = 0; mt < 4; ++mt)
#pragma unroll
        for (int nt = 0; nt < 4; ++nt)
          acc[mt][nt] = __builtin_amdgcn_mfma_f32_16x16x32_bf16(af[mt], bfr[nt], acc[mt][nt], 0, 0, 0);
    }
    __syncthreads();
  }

  // epilogue -> clK (exp(K+bias)) / clV (V+bias), [64][136] each
  u16* clK = smem;                              // bytes [0, 17408)
  u16* clV = smem + 8704;                       // bytes [17408, 34816)
  {
    const int rbase = (lane >> 4) * 4;
    const float* kb = kvbias + b * 512 + (wm ? 256 : 0) + hg * 64;
    if (wm == 0) {                              // K rows
#pragma unroll
      for (int mt = 0; mt < 4; ++mt)
#pragma unroll
        for (int nt = 0; nt < 4; ++nt)
#pragma unroll
          for (int r = 0; r < 4; ++r) {
            const int row = mt * 16 + rbase + r;
            const int col = wn * 64 + nt * 16 + (lane & 15);
            clK[row * 136 + col] = f2bf(__expf(acc[mt][nt][r] + kb[row]));
          }
    } else {                                    // V rows
#pragma unroll
      for (int mt = 0; mt < 4; ++mt)
#pragma unroll
        for (int nt = 0; nt < 4; ++nt)
#pragma unroll
          for (int r = 0; r < 4; ++r) {
            const int row = mt * 16 + rbase + r;
            const int col = wn * 64 + nt * 16 + (lane & 15);
            clV[row * 136 + col] = f2bf(acc[mt][nt][r] + kb[row]);
          }
    }
  }
  __syncthreads();                              // clK + clV visible to all waves

  // att phase: wave = (head hh in pair, n-half)
  const int hh = wave >> 1, nhalf = wave & 1;
  const int bh = b * 8 + hg * 2 + hh;
  f32x4 a2[2][2], al[2];
#pragma unroll
  for (int i = 0; i < 2; ++i) {
    al[i] = (f32x4){0.f, 0.f, 0.f, 0.f};
#pragma unroll
    for (int j = 0; j < 2; ++j) a2[i][j] = (f32x4){0.f, 0.f, 0.f, 0.f};
  }
  short8 ones;
#pragma unroll
  for (int j = 0; j < 8; ++j) ones[j] = (short)0x3F80;   // bf16 1.0

  const int rr = lane & 15, cc8 = (lane >> 4) * 8;
#pragma unroll
  for (int c = 0; c < 2; ++c) {                 // 2 chunks of 32 n per wave
    const int n = (nhalf * 2 + c) * 32 + cc8;
    short8 ek0 = *(const short8*)&clK[(hh * 32 + rr) * 136 + n];
    short8 ek1 = *(const short8*)&clK[(hh * 32 + 16 + rr) * 136 + n];
    short8 v0  = *(const short8*)&clV[(hh * 32 + rr) * 136 + n];
    short8 v1  = *(const short8*)&clV[(hh * 32 + 16 + rr) * 136 + n];
    a2[0][0] = __builtin_amdgcn_mfma_f32_16x16x32_bf16(ek0, v0, a2[0][0], 0, 0, 0);
    a2[0][1] = __builtin_amdgcn_mfma_f32_16x16x32_bf16(ek0, v1, a2[0][1], 0, 0, 0);
    a2[1][0] = __builtin_amdgcn_mfma_f32_16x16x32_bf16(ek1, v0, a2[1][0], 0, 0, 0);
    a2[1][1] = __builtin_amdgcn_mfma_f32_16x16x32_bf16(ek1, v1, a2[1][1], 0, 0, 0);
    al[0]    = __builtin_amdgcn_mfma_f32_16x16x32_bf16(ek0, ones, al[0], 0, 0, 0);
    al[1]    = __builtin_amdgcn_mfma_f32_16x16x32_bf16(ek1, ones, al[1], 0, 0, 0);
  }
  __syncthreads();                              // done reading clK/clV

  // pair-reduce the two n-half waves of each head in LDS, then atomicAdd
  float* red  = (float*)smem;                   // [2][32][34] f32 (8704 B)
  float* redl = red + 2176;                     // [2][32]
  const int dq = (lane >> 4) * 4;
  if (nhalf == 1) {
#pragma unroll
    for (int dh = 0; dh < 2; ++dh) {
#pragma unroll
      for (int eh = 0; eh < 2; ++eh)
#pragma unroll
        for (int j = 0; j < 4; ++j)
          red[hh * 1088 + (dh * 16 + dq + j) * 34 + eh * 16 + rr] = a2[dh][eh][j];
      if (rr == 0)
#pragma unroll
        for (int j = 0; j < 4; ++j) redl[hh * 32 + dh * 16 + dq + j] = al[dh][j];
    }
  }
  __syncthreads();
  if (nhalf == 0) {
    float* ap = att4 + (size_t)bh * 1056;
#pragma unroll
    for (int dh = 0; dh < 2; ++dh) {
#pragma unroll
      for (int eh = 0; eh < 2; ++eh)
#pragma unroll
        for (int j = 0; j < 4; ++j) {
          const int d = dh * 16 + dq + j, e = eh * 16 + rr;
          atomicAdd(&ap[d * 32 + e], a2[dh][eh][j] + red[hh * 1088 + d * 34 + e]);
        }
      if (rr == 0)
#pragma unroll
        for (int j = 0; j < 4; ++j) {
          const int d = dh * 16 + dq + j;
          atomicAdd(&ap[1024 + d], al[dh][j] + redl[hh * 32 + d]);
        }
    }
  }
}

// ------------------------------------------------ w23: W3' = (wp @ blockdiag(att/l) @ Wq) D_wv
// + bias3 = W2 @ qbias + b_proj (n0==0 blocks, from the LDS W2-tile).
__global__ __launch_bounds__(256) void w23_kernel(const u16* __restrict__ wp_bf,
                                                  const u16* __restrict__ wqT,
                                                  const float* __restrict__ att4,
                                                  const float* __restrict__ wvv_g,
                                                  const float* __restrict__ qbias,
                                                  const float* __restrict__ bproj,
                                                  u16* __restrict__ W3,
                                                  float* __restrict__ bias3) {
  __shared__ __align__(16) u16 smem[58880];     // 117760 B
  const int tid = threadIdx.x, wave = tid >> 6, lane = tid & 63;
  const int n0 = blockIdx.x * 128, m0 = blockIdx.y * 128, b = blockIdx.z;

  u16*   lA  = smem;                            // [128][264] u16
  float* asb = (float*)(smem + 33792);          // [8][32][33] f32
  u16*   lB  = smem + 50688;                    // 1024 granules

  // phase 0: as[h][d][e] = att[bh][d][e] / l[bh][d]
  {
    const float* ab = att4 + (size_t)b * 8 * 1056;
    for (int i = tid; i < 8192; i += 256) {
      const int h = i >> 10, d = (i >> 5) & 31, e = i & 31;
      asb[h * 1056 + d * 33 + e] = ab[h * 1056 + d * 32 + e] / ab[h * 1056 + 1024 + d];
    }
  }
  __syncthreads();

  // phase 1: W2-tile via MFMA -> lA ([128 o][256 d] bf16)
  {
    const int r16 = lane & 15, e0 = (lane >> 4) * 8;
#pragma unroll
    for (int hh = 0; hh < 2; ++hh) {
      const int h = wave * 2 + hh;
#pragma unroll
      for (int nt = 0; nt < 2; ++nt) {
        const float* bp = asb + h * 1056 + (nt * 16 + r16) * 33 + e0;
        short8 bfr;
#pragma unroll
        for (int j = 0; j < 8; ++j) bfr[j] = (short)f2bf(bp[j]);
#pragma unroll
        for (int mt = 0; mt < 8; ++mt) {
          const int orow = mt * 16 + r16;
          short8 af = *(const short8*)(wp_bf + (size_t)(m0 + orow) * 256 + h * 32 + e0);
          f32x4 c = __builtin_amdgcn_mfma_f32_16x16x32_bf16(af, bfr, (f32x4){0.f,0.f,0.f,0.f}, 0, 0, 0);
#pragma unroll
          for (int r = 0; r < 4; ++r) {
            const int o = mt * 16 + (lane >> 4) * 4 + r;
            const int d2 = h * 32 + nt * 16 + r16;
            lA[o * 264 + d2] = f2bf(c[r]);
          }
        }
      }
    }
  }
  __syncthreads();

  // bias3 = W2 @ qbias + b_proj (one n0 does it; lA read-only here)
  if (blockIdx.x == 0) {
    const int row = tid >> 1, half = tid & 1;
    const float* qb = qbias + b * 256 + half * 128;
    const u16* la = lA + row * 264 + half * 128;
    float s = 0.f;
#pragma unroll
    for (int d = 0; d < 128; ++d) s += bf2f(la[d]) * qb[d];
    s += __shfl_xor(s, 1);
    if (half == 0) bias3[b * 256 + m0 + row] = s + bproj[m0 + row];
  }

  // phase 2: W3 tile = lA(W2) @ wqT^T, BK=64
  const int lrow = lane >> 3;
  const int kcl  = ((lane & 7) ^ lrow) * 8;
  const u16* pB[4];
#pragma unroll
  for (int j = 0; j < 4; ++j)
    pB[j] = wqT + (size_t)(n0 + j * 32 + wave * 8 + lrow) * 256 + kcl;

  const int wm = wave >> 1, wn = wave & 1;
  f32x4 acc[4][4];
#pragma unroll
  for (int i = 0; i < 4; ++i)
#pragma unroll
    for (int j = 0; j < 4; ++j) acc[i][j] = (f32x4){0.f, 0.f, 0.f, 0.f};

  for (int it = 0; it < 4; ++it) {
#pragma unroll
    for (int j = 0; j < 4; ++j) {
      __builtin_amdgcn_global_load_lds(GLB(pB[j]), LDSP(lB + (j * 256 + wave * 64) * 8), 16, 0, 0);
      pB[j] += 64;
    }
    __syncthreads();
#pragma unroll
    for (int w = 0; w < 2; ++w) {
      const int kcf = w * 4 + (lane >> 4);
      short8 af[4], bfr[4];
#pragma unroll
      for (int mt = 0; mt < 4; ++mt) {
        const int row = wm * 64 + mt * 16 + (lane & 15);
        af[mt] = *(const short8*)&lA[row * 264 + it * 64 + kcf * 8];
      }
#pragma unroll
      for (int nt = 0; nt < 4; ++nt) {
        const int row = wn * 64 + nt * 16 + (lane & 15);
        bfr[nt] = *(const short8*)&lB[(row * 8 + (kcf ^ (row & 7))) * 8];
      }
#pragma unroll
      for (int mt = 0; mt < 4; ++mt)
#pragma unroll
        for (int nt = 0; nt < 4; ++nt)
          acc[mt][nt] = __builtin_amdgcn_mfma_f32_16x16x32_bf16(af[mt], bfr[nt], acc[mt][nt], 0, 0, 0);
    }
    __syncthreads();
  }

  // epilogue: column-scale by wv then bf16 tile -> W3
  u16* cl = smem + 33792;                       // [128][136] u16 (asb dead)
#pragma unroll
  for (int nt = 0; nt < 4; ++nt) {
    const int col = wn * 64 + nt * 16 + (lane & 15);
    const float wvc = wvv_g[b * 256 + n0 + col];
#pragma unroll
    for (int mt = 0; mt < 4; ++mt)
#pragma unroll
      for (int r = 0; r < 4; ++r) {
        const int row = wm * 64 + mt * 16 + (lane >> 4) * 4 + r;
        cl[row * 136 + col] = f2bf(acc[mt][nt][r] * wvc);
      }
  }
  __syncthreads();
  u16* C = W3 + (size_t)b * 65536;
#pragma unroll
  for (int j = 0; j < 8; ++j) {
    const int idx = tid + j * 256;              // 0..2047
    const int row = idx >> 4, chunk = idx & 15;
    *(uint4*)(C + (size_t)(m0 + row) * 256 + n0 + chunk * 8) =
        *(const uint4*)&cl[row * 136 + chunk * 8];
  }
}

// ------------------------------------------------ final gemm: out = W3' @ xT + bias3[b]
__global__ __launch_bounds__(256) void gemm_f32(const u16* __restrict__ A,
                                                const u16* __restrict__ Bt,
                                                const float* __restrict__ bias3,
                                                float* __restrict__ Cm) {
  __shared__ __align__(16) u16 smem[17408];     // 34816 B
  const int tid = threadIdx.x, wave = tid >> 6, lane = tid & 63;
  const int n0 = blockIdx.x * 128, m0 = blockIdx.y * 128, bz = blockIdx.z;
  const u16* Ab = A + (size_t)bz * 65536;
  const u16* Bb = Bt + (size_t)bz * (size_t)NSP * CCH;

  const int lrow = lane >> 3;
  const int kcl  = ((lane & 7) ^ lrow) * 8;
  const u16* pA[4]; const u16* pB[4];
#pragma unroll
  for (int j = 0; j < 4; ++j) {
    const int row = j * 32 + wave * 8 + lrow;
    pA[j] = Ab + (size_t)(m0 + row) * CCH + kcl;
    pB[j] = Bb + (size_t)(n0 + row) * CCH + kcl;
  }
  u16* lA = smem;
  u16* lB = smem + 8192;

  const int wm = wave >> 1, wn = wave & 1;
  f32x4 acc[4][4];
#pragma unroll
  for (int i = 0; i < 4; ++i)
#pragma unroll
    for (int j = 0; j < 4; ++j) acc[i][j] = (f32x4){0.f, 0.f, 0.f, 0.f};

  for (int it = 0; it < 4; ++it) {              // K = 256, BK = 64
#pragma unroll
    for (int j = 0; j < 4; ++j) {
      __builtin_amdgcn_global_load_lds(GLB(pA[j]), LDSP(lA + (j * 256 + wave * 64) * 8), 16, 0, 0);
      __builtin_amdgcn_global_load_lds(GLB(pB[j]), LDSP(lB + (j * 256 + wave * 64) * 8), 16, 0, 0);
      pA[j] += 64; pB[j] += 64;
    }
    __syncthreads();
#pragma unroll
    for (int w = 0; w < 2; ++w) {
      const int kcf = w * 4 + (lane >> 4);
      short8 af[4], bfr[4];
#pragma unroll
      for (int mt = 0; mt < 4; ++mt) {
        const int row = wm * 64 + mt * 16 + (lane & 15);
        af[mt] = *(const short8*)&lA[(row * 8 + (kcf ^ (row & 7))) * 8];
      }
#pragma unroll
      for (int nt = 0; nt < 4; ++nt) {
        const int row = wn * 64 + nt * 16 + (lane & 15);
        bfr[nt] = *(const short8*)&lB[(row * 8 + (kcf ^ (row & 7))) * 8];
      }
#pragma unroll
      for (int mt = 0; mt < 4; ++mt)
#pragma unroll
        for (int nt = 0; nt < 4; ++nt)
          acc[mt][nt] = __builtin_amdgcn_mfma_f32_16x16x32_bf16(af[mt], bfr[nt], acc[mt][nt], 0, 0, 0);
    }
    __syncthreads();
  }

  float* clf = (float*)smem;                    // [64][132] fp32 per pass
  float* C = Cm + (size_t)bz * (size_t)CCH * NSP;
#pragma unroll
  for (int pass = 0; pass < 2; ++pass) {
    if (wm == pass) {
#pragma unroll
      for (int mt = 0; mt < 4; ++mt)
#pragma unroll
        for (int nt = 0; nt < 4; ++nt)
#pragma unroll
          for (int r = 0; r < 4; ++r) {
            const int rl = mt * 16 + (lane >> 4) * 4 + r;
            const int col = wn * 64 + nt * 16 + (lane & 15);
            clf[rl * 132 + col] = acc[mt][nt][r] + bias3[bz * 256 + m0 + pass * 64 + rl];
          }
    }
    __syncthreads();
#pragma unroll
    for (int j = 0; j < 8; ++j) {
      const int idx = tid + j * 256;
      const int row = idx >> 5, chunk = idx & 31;
      *(float4*)(C + (size_t)(m0 + pass * 64 + row) * NSP + n0 + chunk * 4) =
          *(const float4*)&clf[row * 132 + chunk * 4];
    }
    __syncthreads();
  }
}

// ------------------------------------------------ launch (5 kernels)
extern "C" void kernel_launch(void* const* d_in, const int* in_sizes, int n_in,
                              void* d_out, int out_size, void* d_ws, size_t ws_size,
                              hipStream_t stream) {
  const float* x      = (const float*)d_in[0];
  const float* gn_w   = (const float*)d_in[1];
  const float* gn_b   = (const float*)d_in[2];
  const float* w_qkv  = (const float*)d_in[3];
  const float* w_proj = (const float*)d_in[4];
  const float* b_proj = (const float*)d_in[5];
  float* out = (float*)d_out;

  char* ws = (char*)d_ws;
  u16*   xT     = (u16*)ws;                                 // 32 MiB [b][n][c] raw bf16
  u16*   wpbf   = (u16*)(ws + 33554432ull);                 // 128 KiB
  u16*   wqT    = (u16*)(ws + 33685504ull);                 // 128 KiB
  u16*   Akv    = (u16*)(ws + 33816576ull);                 // 4 MiB [b][512][256]
  u16*   W3     = (u16*)(ws + 38010880ull);                 // 2 MiB [b][256][256]
  float* att4   = (float*)(ws + 40108032ull);               // 540672 B
  float* gstat  = (float*)(ws + 40648704ull);               // 4 KiB (512 float2)
  float* wvv_g  = (float*)(ws + 40652800ull);               // 16 KiB
  float* qbias  = (float*)(ws + 40669184ull);               // 16 KiB
  float* kvbias = (float*)(ws + 40685568ull);               // 32 KiB
  float* bias3  = (float*)(ws + 40718336ull);               // 16 KiB

  hipMemsetAsync(gstat, 0, 4096, stream);
  xprep_kernel<<<4308, 256, 0, stream>>>(x, w_qkv, w_proj, xT, wpbf, wqT, att4, gstat);
  wfold_kernel<<<dim3(24, 16), 256, 0, stream>>>(w_qkv, gn_w, gn_b, gstat,
                                                 Akv, wvv_g, qbias, kvbias);
  gemm_kv_att<<<dim3(32, 4, 16), 256, 0, stream>>>(Akv, xT, kvbias, att4);
  w23_kernel<<<dim3(2, 2, 16), 256, 0, stream>>>(wpbf, wqT, att4, wvv_g, qbias,
                                                 b_proj, W3, bias3);
  gemm_f32<<<dim3(32, 2, 16), 256, 0, stream>>>(W3, xT, bias3, out);
}